// Round 1
// 195.004 us; speedup vs baseline: 1.0095x; 1.0095x over previous
//
#include <hip/hip_runtime.h>

#define NROWS 4096
#define DCOLS 4096
#define MARGIN 1.2f

// Native clang vector type — maps to a 4-VGPR quad for the asm constraint.
typedef float vfloat4 __attribute__((ext_vector_type(4)));

// R6: fully cache-bypassing streaming reads.
// Theory: the harness's 256 MiB workspace poison fill (41 us, 82% HBM peak,
// visible as fillBufferAligned in rocprof) leaves the Infinity Cache (MALL)
// entirely dirty right before this kernel runs. Normal AND nt-builtin reads
// still ALLOCATE MALL lines on miss, forcing dirty-victim writebacks to HBM
// concurrently with our 128 MiB of mandatory reads -> ~2.8 TB/s delivered,
// ~48 us (R1-R4 plateau). __builtin_nontemporal_load only sets the `nt` bit
// (L2 retention hint). Full bypass needs `sc0 sc1 nt` on the load, which
// only inline asm can emit on gfx950.
__global__ __launch_bounds__(256) void row_loss_kernel(
    const float* __restrict__ x0, const float* __restrict__ x1,
    const int* __restrict__ y, float* __restrict__ row_out) {
    const int row = blockIdx.x;
    const unsigned long long abase =
        (unsigned long long)(x0 + (size_t)row * DCOLS);
    const unsigned long long bbase =
        (unsigned long long)(x1 + (size_t)row * DCOLS);

    // 1024 float4 per row / 256 threads = 4 iters, coalesced 1 KiB/wave.
    // Issue all 8 loads first (max MLP per thread), then one waitcnt.
    vfloat4 va[4], vb[4];
    #pragma unroll
    for (int k = 0; k < 4; ++k) {
        const unsigned long long off =
            (unsigned long long)(threadIdx.x + (unsigned)k * 256u) * 16ull;
        const unsigned long long pa = abase + off;
        const unsigned long long pb = bbase + off;
        // sc0 sc1 nt = bypass L1/L2/MALL: no allocation -> no dirty-victim
        // writebacks from the poison-filled LLC.
        asm volatile("global_load_dwordx4 %0, %1, off sc0 sc1 nt"
                     : "=&v"(va[k]) : "v"(pa));
        asm volatile("global_load_dwordx4 %0, %1, off sc0 sc1 nt"
                     : "=&v"(vb[k]) : "v"(pb));
    }
    // Rule #18: compiler will hoist the (register-only) FMAs past an
    // inline-asm waitcnt despite the memory clobber; sched_barrier(0)
    // is the required fence.
    asm volatile("s_waitcnt vmcnt(0)" ::: "memory");
    __builtin_amdgcn_sched_barrier(0);

    float s = 0.f;
    #pragma unroll
    for (int k = 0; k < 4; ++k) {
        const float dx = va[k].x - vb[k].x;
        const float dy = va[k].y - vb[k].y;
        const float dz = va[k].z - vb[k].z;
        const float dw = va[k].w - vb[k].w;
        s = fmaf(dx, dx, s);
        s = fmaf(dy, dy, s);
        s = fmaf(dz, dz, s);
        s = fmaf(dw, dw, s);
    }

    // wave64 reduction
    #pragma unroll
    for (int off = 32; off > 0; off >>= 1) s += __shfl_down(s, off, 64);

    __shared__ float smem[4];
    const int lane = threadIdx.x & 63;
    const int wid = threadIdx.x >> 6;
    if (lane == 0) smem[wid] = s;
    __syncthreads();

    if (threadIdx.x == 0) {
        float d2 = (smem[0] + smem[1]) + (smem[2] + smem[3]);
        float dist = sqrtf(d2);
        float clamped = fmaxf(MARGIN - dist, 0.f);
        float yf = (float)y[row];
        row_out[row] = yf * d2 + (1.f - yf) * clamped;
    }
}

__global__ __launch_bounds__(256) void final_reduce_kernel(
    const float* __restrict__ row_out, float* __restrict__ out) {
    float s = 0.f;
    for (int i = threadIdx.x; i < NROWS; i += 256) s += row_out[i];

    #pragma unroll
    for (int off = 32; off > 0; off >>= 1) s += __shfl_down(s, off, 64);

    __shared__ float smem[4];
    const int lane = threadIdx.x & 63;
    const int wid = threadIdx.x >> 6;
    if (lane == 0) smem[wid] = s;
    __syncthreads();

    if (threadIdx.x == 0) {
        out[0] = ((smem[0] + smem[1]) + (smem[2] + smem[3])) * (1.f / (2.f * (float)NROWS));
    }
}

extern "C" void kernel_launch(void* const* d_in, const int* in_sizes, int n_in,
                              void* d_out, int out_size, void* d_ws, size_t ws_size,
                              hipStream_t stream) {
    const float* x0 = (const float*)d_in[0];
    const float* x1 = (const float*)d_in[1];
    // d_in[2], d_in[3] (x_c_0, x_c_1) are dead in the reference computation.
    const int* y = (const int*)d_in[4];

    float* row_out = (float*)d_ws;  // 4096 floats = 16 KiB scratch
    float* out = (float*)d_out;

    row_loss_kernel<<<NROWS, 256, 0, stream>>>(x0, x1, y, row_out);
    final_reduce_kernel<<<1, 256, 0, stream>>>(row_out, out);
}